// Round 1
// baseline (569.311 us; speedup 1.0000x reference)
//
#include <hip/hip_runtime.h>

// Problem constants (match reference)
#define BB    4
#define CC    32
#define HH    32
#define WW    1024
#define PATCH 21
#define DIL   2
#define RAD   10            // (PATCH-1)/2
#define PADW  20            // DIL*RAD : max displacement
#define CHUNK 4             // channels staged per LDS pass
#define LROW  (WW + 2*PADW) // 1064 floats per staged x2 row (deinterleaved 532 even + 532 odd)
#define EHALF (LROW/2)      // 532
#define NG    (LROW/8)      // 133 8-float granules per row

// Block: (h-pair, b*pi, pj-group). 256 threads = 128 w-positions x 2 h rows.
// Thread (tw, th) covers w = 8*tw .. 8*tw+7 for h = 2*h2+th.   Wout=8 halves
// LDS window bytes/FMA vs the old Wout=4 layout; the even/odd deinterleave
// keeps ds_read_b128 lane-stride at 16B (conflict-free) despite Wout=8.
// z groups {pj 0..10, pj 11..20}: 2 stagings of each x2 row instead of 3.
template <int PJ0, int TPT>
__device__ __forceinline__ void corr_body(const float* __restrict__ x1,
                                          const float* __restrict__ x2,
                                          float* __restrict__ out,
                                          float* __restrict__ sx2 /* [CHUNK*2*LROW] */) {
    const int tid = threadIdx.x;
    const int tw  = tid & 127;           // w-position index (w = 8*tw)
    const int th  = tid >> 7;            // which h row of the pair
    const int h2  = blockIdx.x;          // 0..15
    const int bp  = blockIdx.y;          // b*PATCH + pi
    const int b   = bp / PATCH;
    const int pi  = bp - b * PATCH;
    const int r20 = 2 * (h2 + pi - RAD); // x2 row for th=0 (even); th=1 uses r20+1
    const int h   = 2 * h2 + th;
    const int w8  = tw * 8;

    float* outp = out + (((size_t)(b * PATCH * PATCH + pi * PATCH + PJ0)) * HH + h) * WW + w8;

    if ((unsigned)r20 > 30u) {
        // r20 is even => the h-pair's two source rows are both OOB together.
        float4 z = make_float4(0.f, 0.f, 0.f, 0.f);
#pragma unroll
        for (int j = 0; j < TPT; j++) {
            *(float4*)(outp + (size_t)j * HH * WW)     = z;
            *(float4*)(outp + (size_t)j * HH * WW + 4) = z;
        }
        return;
    }

    float acc[TPT][8];
#pragma unroll
    for (int j = 0; j < TPT; j++)
#pragma unroll
        for (int k = 0; k < 8; k++) acc[j][k] = 0.f;

    constexpr int D  = PJ0 & 3;    // window base misalignment within a float4 (0 or 3)
    constexpr int EB = PJ0 & ~3;   // aligned window base offset (floats, within half-row)

    for (int cc = 0; cc < CC; cc += CHUNK) {
        __syncthreads();
        // Stage CHUNK channels x 2 rows with +/-20 halo, zero-padded, DEINTERLEAVED:
        // padded col p = u+20: p even -> E[p/2] (row[0..532)), p odd -> O[p/2] (row[532..1064)).
        // Each lane loads an 8-float granule (two float4, each fully in or out of
        // [0,1024) since granule base u0 = 8g-20 is 4-aligned) and writes two b128s.
#pragma unroll
        for (int t = 0; t < (CHUNK * 2 * NG + 255) / 256; t++) {
            int idx = tid + t * 256;
            if (idx < CHUNK * 2 * NG) {
                int c  = idx / (2 * NG);
                int r  = idx - c * (2 * NG);
                int rr = r / NG;
                int g  = r - rr * NG;
                int u0 = 8 * g - PADW;
                const float* src = x2 + ((size_t)(b * CC + cc + c) * HH + (r20 + rr)) * WW;
                float4 v0 = make_float4(0.f, 0.f, 0.f, 0.f);
                float4 v1 = v0;
                if (u0 >= 0     && u0     <= WW - 4) v0 = *(const float4*)(src + u0);
                if (u0 + 4 >= 0 && u0 + 4 <= WW - 4) v1 = *(const float4*)(src + u0 + 4);
                float* dst = sx2 + (c * 2 + rr) * LROW + 4 * g;
                *(float4*)dst           = make_float4(v0.x, v0.z, v1.x, v1.z); // evens
                *(float4*)(dst + EHALF) = make_float4(v0.y, v0.w, v1.y, v1.w); // odds
            }
        }
        __syncthreads();

#pragma unroll
        for (int cl = 0; cl < CHUNK; cl++) {
            const float* x1p = x1 + ((size_t)(b * CC + cc + cl) * HH + h) * WW + w8;
            float4 a0 = *(const float4*)x1p;
            float4 a1 = *(const float4*)(x1p + 4);
            const float a[8] = {a0.x, a0.y, a0.z, a0.w, a1.x, a1.y, a1.z, a1.w};

            // Window for taps PJ0..PJ0+TPT-1 at w8..w8+7: evens E[4tw+PJ0 + 0..TPT+2],
            // odds same range. Read 4 aligned float4 from each half (lane stride 16B).
            const float* eb = sx2 + (cl * 2 + th) * LROW + 4 * tw + EB;
            float ef[16], of[16];
#pragma unroll
            for (int v = 0; v < 4; v++) {
                *(float4*)&ef[4 * v] = *(const float4*)(eb + 4 * v);
                *(float4*)&of[4 * v] = *(const float4*)(eb + EHALF + 4 * v);
            }
#pragma unroll
            for (int j = 0; j < TPT; j++)
#pragma unroll
                for (int k = 0; k < 8; k++) {
                    // u = w8+k+2*(PJ0+j)-20 -> parity k; index D+j+(k>>1) (max 15, fits)
                    float wv = (k & 1) ? of[D + j + (k >> 1)] : ef[D + j + (k >> 1)];
                    acc[j][k] = fmaf(a[k], wv, acc[j][k]);
                }
        }
    }

    const float inv_c = 1.0f / (float)CC;
#pragma unroll
    for (int j = 0; j < TPT; j++) {
        float4 o0, o1;
        float* p0 = (float*)&o0;
        float* p1 = (float*)&o1;
#pragma unroll
        for (int k = 0; k < 4; k++) {
            float v = acc[j][k] * inv_c;
            p0[k] = v > 0.f ? v : 0.1f * v;
        }
#pragma unroll
        for (int k = 0; k < 4; k++) {
            float v = acc[j][4 + k] * inv_c;
            p1[k] = v > 0.f ? v : 0.1f * v;
        }
        *(float4*)(outp + (size_t)j * HH * WW)     = o0;
        *(float4*)(outp + (size_t)j * HH * WW + 4) = o1;
    }
}

// __launch_bounds__(256, 3): 3 waves/EU -> VGPR cap 170, 3 blocks/CU (12 waves).
// acc[11][8]=88 + 32 window + 8 x1 + addressing ~ 150 VGPR. LDS 34 KB/block -> 102 KB/CU.
__global__ __launch_bounds__(256, 3)
void corr_kernel(const float* __restrict__ x1, const float* __restrict__ x2,
                 float* __restrict__ out) {
    __shared__ float sx2[CHUNK * 2 * LROW];   // 34 KB, shared by both tap groups
    if (blockIdx.z == 0) corr_body<0, 11>(x1, x2, out, sx2);
    else                 corr_body<11, 10>(x1, x2, out, sx2);
}

extern "C" void kernel_launch(void* const* d_in, const int* in_sizes, int n_in,
                              void* d_out, int out_size, void* d_ws, size_t ws_size,
                              hipStream_t stream) {
    const float* x1 = (const float*)d_in[0];
    const float* x2 = (const float*)d_in[1];
    float* out = (float*)d_out;

    dim3 grid(HH / 2, BB * PATCH, 2);   // (h-pairs, b*pi, pj-groups {0..10, 11..20})
    dim3 block(256, 1, 1);
    corr_kernel<<<grid, block, 0, stream>>>(x1, x2, out);
}

// Round 2
// 503.623 us; speedup vs baseline: 1.1304x; 1.1304x over previous
//
#include <hip/hip_runtime.h>

// Problem constants (match reference)
#define BB    4
#define CC    32
#define HH    32
#define WW    1024
#define PATCH 21
#define DIL   2
#define RAD   10            // (PATCH-1)/2
#define PADW  20            // DIL*RAD : max displacement
#define CHUNK 4             // channels staged per LDS pass
#define LROW  (WW + 2*PADW) // 1064 floats per staged x2 row (deinterleaved 532 even + 532 odd)
#define EHALF (LROW/2)      // 532
#define NG    (LROW/8)      // 133 8-float granules per row

// Block: 128 threads, one (h, b*pi, pj-group). Thread tw covers w = 8*tw..8*tw+7.
// Wout=8 keeps LDS window bytes/FMA at ~1.7 B (vs 2.5 for Wout=4); the even/odd
// deinterleave keeps ds_read_b128 lane-stride at 16 B (conflict-free).
// R1 LESSON: acc[11][8]=88 floats spilled to scratch (VGPR_Count=84, 500 MB of
// scratch HBM traffic). TPT=7 x 3 groups keeps acc at 56 floats -> ~111 VGPR.
template <int PJ0>
__device__ __forceinline__ void corr_body(const float* __restrict__ x1,
                                          const float* __restrict__ x2,
                                          float* __restrict__ out,
                                          float* __restrict__ sx2 /* [CHUNK*LROW] LDS */) {
    constexpr int TPT = 7;
    constexpr int D   = PJ0 & 3;               // window base misalignment (0,3,2)
    constexpr int EB  = PJ0 & ~3;              // aligned base offset within half-row
    constexpr int NV4 = (D + TPT + 3 + 3) / 4; // float4 loads per half: 3,4,3

    const int tid = threadIdx.x;               // 0..127
    const int h   = blockIdx.x;                // 0..31
    const int bp  = blockIdx.y;                // b*PATCH + pi
    const int b   = bp / PATCH;
    const int pi  = bp - b * PATCH;
    const int r2  = h + DIL * (pi - RAD);      // x2 source row
    const int w8  = tid * 8;

    float* outp = out + (((size_t)(b * PATCH * PATCH + pi * PATCH + PJ0)) * HH + h) * WW + w8;

    if ((unsigned)r2 >= (unsigned)HH) {
        float4 z = make_float4(0.f, 0.f, 0.f, 0.f);
#pragma unroll
        for (int j = 0; j < TPT; j++) {
            *(float4*)(outp + (size_t)j * HH * WW)     = z;
            *(float4*)(outp + (size_t)j * HH * WW + 4) = z;
        }
        return;
    }

    float acc[TPT][8];
#pragma unroll
    for (int j = 0; j < TPT; j++)
#pragma unroll
        for (int k = 0; k < 8; k++) acc[j][k] = 0.f;

    for (int cc = 0; cc < CC; cc += CHUNK) {
        __syncthreads();
        // Stage CHUNK channels of row r2 with +/-20 halo, zero-padded, DEINTERLEAVED:
        // padded col p = u+20: even -> sx2[c*LROW + p/2], odd -> sx2[c*LROW + EHALF + p/2].
        // Each lane handles an 8-float granule (two float4, each fully in or out of
        // [0,1024) since u0 = 8g-20 is 4-aligned) and emits two contiguous b128 writes.
#pragma unroll
        for (int t = 0; t < (CHUNK * NG + 127) / 128; t++) {
            int idx = tid + t * 128;
            if (idx < CHUNK * NG) {
                int c  = idx / NG;
                int g  = idx - c * NG;
                int u0 = 8 * g - PADW;
                const float* src = x2 + ((size_t)(b * CC + cc + c) * HH + r2) * WW;
                float4 v0 = make_float4(0.f, 0.f, 0.f, 0.f);
                float4 v1 = v0;
                if (u0 >= 0     && u0     <= WW - 4) v0 = *(const float4*)(src + u0);
                if (u0 + 4 >= 0 && u0 + 4 <= WW - 4) v1 = *(const float4*)(src + u0 + 4);
                float* dst = sx2 + c * LROW + 4 * g;
                *(float4*)dst           = make_float4(v0.x, v0.z, v1.x, v1.z); // evens
                *(float4*)(dst + EHALF) = make_float4(v0.y, v0.w, v1.y, v1.w); // odds
            }
        }
        __syncthreads();

#pragma unroll
        for (int cl = 0; cl < CHUNK; cl++) {
            const float* x1p = x1 + ((size_t)(b * CC + cc + cl) * HH + h) * WW + w8;
            float4 a0 = *(const float4*)x1p;
            float4 a1 = *(const float4*)(x1p + 4);
            const float a[8] = {a0.x, a0.y, a0.z, a0.w, a1.x, a1.y, a1.z, a1.w};

            // Window floats needed per half: indices D .. D+TPT+2 (rel. to 4*tw+EB).
            const float* eb = sx2 + cl * LROW + 4 * tid + EB;
            float ef[NV4 * 4], of[NV4 * 4];
#pragma unroll
            for (int v = 0; v < NV4; v++) {
                *(float4*)&ef[4 * v] = *(const float4*)(eb + 4 * v);
                *(float4*)&of[4 * v] = *(const float4*)(eb + EHALF + 4 * v);
            }
#pragma unroll
            for (int j = 0; j < TPT; j++)
#pragma unroll
                for (int k = 0; k < 8; k++) {
                    // u = w8+k+2*(PJ0+j)-20 -> parity k; half-index D+j+(k>>1)
                    float wv = (k & 1) ? of[D + j + (k >> 1)] : ef[D + j + (k >> 1)];
                    acc[j][k] = fmaf(a[k], wv, acc[j][k]);
                }
        }
    }

    const float inv_c = 1.0f / (float)CC;
#pragma unroll
    for (int j = 0; j < TPT; j++) {
        float4 o0, o1;
        float* p0 = (float*)&o0;
        float* p1 = (float*)&o1;
#pragma unroll
        for (int k = 0; k < 4; k++) {
            float v = acc[j][k] * inv_c;
            p0[k] = v > 0.f ? v : 0.1f * v;
        }
#pragma unroll
        for (int k = 0; k < 4; k++) {
            float v = acc[j][4 + k] * inv_c;
            p1[k] = v > 0.f ? v : 0.1f * v;
        }
        *(float4*)(outp + (size_t)j * HH * WW)     = o0;
        *(float4*)(outp + (size_t)j * HH * WW + 4) = o1;
    }
}

// __launch_bounds__(128, 4): 4 waves/EU -> VGPR cap 128. Estimated need ~111
// (56 acc + <=32 window + 8 x1 + addressing). LDS 17 KB/block -> 9 blocks by
// LDS; VGPR allows 8 blocks (16 waves/CU).
__global__ __launch_bounds__(128, 4)
void corr_kernel(const float* __restrict__ x1, const float* __restrict__ x2,
                 float* __restrict__ out) {
    __shared__ float sx2[CHUNK * LROW];   // 17 KB, shared by all tap groups
    if (blockIdx.z == 0)      corr_body<0>(x1, x2, out, sx2);
    else if (blockIdx.z == 1) corr_body<7>(x1, x2, out, sx2);
    else                      corr_body<14>(x1, x2, out, sx2);
}

extern "C" void kernel_launch(void* const* d_in, const int* in_sizes, int n_in,
                              void* d_out, int out_size, void* d_ws, size_t ws_size,
                              hipStream_t stream) {
    const float* x1 = (const float*)d_in[0];
    const float* x2 = (const float*)d_in[1];
    float* out = (float*)d_out;

    dim3 grid(HH, BB * PATCH, 3);   // (h, b*pi, pj-groups {0..6, 7..13, 14..20})
    dim3 block(128, 1, 1);
    corr_kernel<<<grid, block, 0, stream>>>(x1, x2, out);
}

// Round 3
// 341.470 us; speedup vs baseline: 1.6672x; 1.4749x over previous
//
#include <hip/hip_runtime.h>
#include <stdint.h>

// Problem constants (match reference)
#define BB     4
#define CC     32
#define HH     32
#define WW     1024
#define PATCH  21
#define DIL    2
#define RAD    10
#define PADW   20                 // DIL*RAD : max displacement
#define CHUNKC 2                  // channels staged per pass
#define NP     (CC / CHUNKC)      // 16 passes
#define NGR    266                // float4 granules per padded row ((1024+40)/4)
#define ROWF   (NGR * 4)          // 1064 floats per channel row
#define BUFF   (CHUNKC * ROWF)    // 2128 floats per buffer

// R2 LESSON: all pipes <35% busy => latency-bound (loads issued AFTER barrier,
// waited immediately, 8x per block, 11 waves/CU). This version: DMA staging
// via global_load_lds issued BEFORE compute of the previous chunk (2-phase
// pipeline, one barrier/pass), bank-conflict-free via granule XOR swizzle
// applied to BOTH the global source address and the LDS read address (rule #21).
typedef __attribute__((address_space(3))) uint32_t lds_u32_t;
typedef __attribute__((address_space(1))) const uint32_t glb_u32_t;

// Involution on float4-granule index within a 266-granule row. Makes the
// Wout=8 read pattern (slot = 2*lane + const, +0..3) hit 8 distinct bank
// quads per 8-lane phase -> conflict-free ds_read_b128.
__device__ __forceinline__ int swz(int s) { return s ^ ((s >> 3) & 1); }

// Issue DMA for CHUNKC channels of row r2 into sbuf. LDS dest is linear
// (slot = granule idx; HW writes wave-uniform base + lane*16); the swizzle is
// realized by fetching global granule swz(q) into physical slot q.
// Granules with swz(q) outside [5,260] are fully out-of-range (PADW%4==0) and
// are SKIPPED -> their slots keep the prologue zeros forever.
__device__ __forceinline__ void stage_dma(const float* __restrict__ x2c0,
                                          float* __restrict__ sbuf, int tid) {
#pragma unroll
    for (int t = 0; t < 3; t++) {
        const int idx = tid + t * 256;
        if (idx < CHUNKC * NGR) {
            const int c  = (idx >= NGR) ? 1 : 0;
            const int q  = idx - c * NGR;
            const int gq = swz(q);
            const int base_gran = (tid & ~63) + t * 256;   // wave-uniform
            lds_u32_t* ldst = (lds_u32_t*)(sbuf + base_gran * 4);
            const float* src = x2c0 + (size_t)c * (HH * WW) + (gq * 4 - PADW);
            if (gq >= 5 && gq <= 260)
                __builtin_amdgcn_global_load_lds((glb_u32_t*)src, ldst, 16, 0, 0);
        }
    }
}

// One half-block's FMA work for one pass: NT taps starting at PJ0, Wout=8.
template <int PJ0, int NT, int NACC>
__device__ __forceinline__ void compute_half(const float* __restrict__ x1p,
                                             const float* __restrict__ sbuf,
                                             int tw, float (&acc)[NACC][8]) {
    constexpr int PJ0A = PJ0 & ~1;               // float4-alignable tap base
    constexpr int DD   = 2 * (PJ0 - PJ0A);       // 0 or 2 float offset
    constexpr int NV4  = (DD + 8 + 2 * (NT - 1) + 3) / 4;  // 4,3,3 loads
    const int g0 = 2 * tw + PJ0A / 2;            // logical window base granule
    int ps[NV4];                                 // physical byte/4 offsets (static idx)
#pragma unroll
    for (int r = 0; r < NV4; r++) ps[r] = 4 * swz(g0 + r);

#pragma unroll
    for (int c = 0; c < CHUNKC; c++) {
        const float* xp = x1p + (size_t)c * (HH * WW);
        float4 a0 = *(const float4*)xp;
        float4 a1 = *(const float4*)(xp + 4);
        const float a[8] = {a0.x, a0.y, a0.z, a0.w, a1.x, a1.y, a1.z, a1.w};
        const float* row = sbuf + c * ROWF;
        float win[NV4 * 4];
#pragma unroll
        for (int r = 0; r < NV4; r++)
            *(float4*)&win[4 * r] = *(const float4*)(row + ps[r]);
        // win float f  <=> padded col 4*g0+f  <=> u = w8 + f - 20 - 2*PJ0A + ... :
        // tap PJ0+j, output w8+k needs f = DD + k + 2*j   (max 13 < NV4*4)
#pragma unroll
        for (int j = 0; j < NT; j++)
#pragma unroll
            for (int k = 0; k < 8; k++)
                acc[j][k] = fmaf(a[k], win[DD + k + 2 * j], acc[j][k]);
    }
}

template <int NT, int NACC>
__device__ __forceinline__ void epilogue(float* __restrict__ outp,
                                         const float (&acc)[NACC][8], float inv_c) {
#pragma unroll
    for (int j = 0; j < NT; j++) {
        float4 o0, o1;
        float* p0 = (float*)&o0;
        float* p1 = (float*)&o1;
#pragma unroll
        for (int k = 0; k < 4; k++) {
            float v0 = acc[j][k] * inv_c;
            float v1 = acc[j][4 + k] * inv_c;
            p0[k] = v0 > 0.f ? v0 : 0.1f * v0;
            p1[k] = v1 > 0.f ? v1 : 0.1f * v1;
        }
        *(float4*)(outp + (size_t)j * HH * WW)     = o0;
        *(float4*)(outp + (size_t)j * HH * WW + 4) = o1;
    }
}

// Block: 256 threads = 128 w-positions (Wout=8) x 2 tap-halves.
// th2=0 -> taps PJ0_LO..+NT_LO-1, th2=1 -> PJ0_HI..+NT_HI-1 (wave-uniform split,
// no barriers inside the divergent region).
template <int PJ0_LO, int NT_LO, int PJ0_HI, int NT_HI>
__device__ __forceinline__ void corr_body(const float* __restrict__ x1,
                                          const float* __restrict__ x2,
                                          float* __restrict__ out,
                                          float* __restrict__ sx2) {
    const int tid = threadIdx.x;
    const int tw  = tid & 127;
    const int th2 = tid >> 7;
    const int h   = blockIdx.x;
    const int bp  = blockIdx.y;           // b*PATCH + pi
    const int b   = bp / PATCH;
    const int pi  = bp - b * PATCH;
    const int r2  = h + DIL * (pi - RAD); // x2 source row
    const int w8  = tw * 8;
    const int PJ0 = th2 ? PJ0_HI : PJ0_LO;
    const int NT  = th2 ? NT_HI : NT_LO;

    float* outp = out + (((size_t)(b * PATCH * PATCH + pi * PATCH + PJ0)) * HH + h) * WW + w8;

    if ((unsigned)r2 >= (unsigned)HH) {
        // whole displacement row OOB -> zeros (block-uniform: no barriers executed)
        float4 z = make_float4(0.f, 0.f, 0.f, 0.f);
        for (int j = 0; j < NT; j++) {
            *(float4*)(outp + (size_t)j * HH * WW)     = z;
            *(float4*)(outp + (size_t)j * HH * WW + 4) = z;
        }
        return;
    }

    // Prologue: zero the 10 never-staged (OOB) granules of each of the 4
    // channel-rows (2 buffers x 2 channels). Physical OOB slot set is
    // {0..4, 261..265} (sigma maps it to itself).
    if (tid < 40) {
        const int rr = tid / 10, g = tid % 10;
        const int slot = (g < 5) ? g : (256 + g);   // 0..4 / 261..265
        float4 z = make_float4(0.f, 0.f, 0.f, 0.f);
        *(float4*)(sx2 + rr * ROWF + 4 * slot) = z;
    }

    const float* x2base = x2 + ((size_t)(b * CC) * HH + r2) * WW;   // + c*HH*WW
    const float* x1base = x1 + ((size_t)(b * CC) * HH + h) * WW + w8;

    stage_dma(x2base, sx2, tid);          // chunk 0 -> buf 0
    __syncthreads();                      // drains DMA (vmcnt) + zero-writes

    float acc[NT_LO][8];
#pragma unroll
    for (int j = 0; j < NT_LO; j++)
#pragma unroll
        for (int k = 0; k < 8; k++) acc[j][k] = 0.f;

    for (int p = 0; p < NP; p++) {
        // issue next chunk's DMA BEFORE computing this one: HBM/L2 latency
        // hides under the FMA phase; pass-end __syncthreads drains it.
        if (p + 1 < NP)
            stage_dma(x2base + (size_t)(p + 1) * CHUNKC * HH * WW,
                      sx2 + ((p + 1) & 1) * BUFF, tid);
        const float* bufc = sx2 + (p & 1) * BUFF;
        const float* x1p  = x1base + (size_t)p * CHUNKC * HH * WW;
        if (th2 == 0) compute_half<PJ0_LO, NT_LO>(x1p, bufc, tw, acc);
        else          compute_half<PJ0_HI, NT_HI>(x1p, bufc, tw, acc);
        if (p + 1 < NP) __syncthreads();
    }

    const float inv_c = 1.0f / (float)CC;
    if (th2 == 0) epilogue<NT_LO>(outp, acc, inv_c);
    else          epilogue<NT_HI>(outp, acc, inv_c);
}

// acc 32 + win 16 + a 8 + addressing ~20 => ~78 VGPR; (256,6) caps at 85
// -> 6 blocks/CU (24 waves). LDS 17 KB/block (2 x 2128 floats) -> not binding.
__global__ __launch_bounds__(256, 6)
void corr_kernel(const float* __restrict__ x1, const float* __restrict__ x2,
                 float* __restrict__ out) {
    __shared__ float sx2[2 * BUFF];
    if (blockIdx.z == 0)      corr_body<0, 4, 4, 4>(x1, x2, out, sx2);
    else if (blockIdx.z == 1) corr_body<8, 4, 12, 4>(x1, x2, out, sx2);
    else                      corr_body<16, 3, 19, 2>(x1, x2, out, sx2);
}

extern "C" void kernel_launch(void* const* d_in, const int* in_sizes, int n_in,
                              void* d_out, int out_size, void* d_ws, size_t ws_size,
                              hipStream_t stream) {
    const float* x1 = (const float*)d_in[0];
    const float* x2 = (const float*)d_in[1];
    float* out = (float*)d_out;

    dim3 grid(HH, BB * PATCH, 3);   // (h, b*pi, tap-groups {0-7, 8-15, 16-20})
    dim3 block(256, 1, 1);
    corr_kernel<<<grid, block, 0, stream>>>(x1, x2, out);
}